// Round 8
// baseline (9452.920 us; speedup 1.0000x reference)
//
#include <hip/hip_runtime.h>
#include <stdint.h>

#define SEQB 512
#define BATCH 32
#define EDIM 256
#define HIDN 256
#define HH2 512
#define RDIM 128
#define NEnt 64
#define NSt 64
#define NNODE 128
#define NHELP 112
#define HPW 112         // per-group arrive threshold: 14 helpers x 8 waves
#define NROWS 3584      // 1536 (U0) + 1536 (U1) + 512 (Uf)
#define TERMEVT 0xFFFFFFFFu
#define SCOPE_AGENT __HIP_MEMORY_SCOPE_AGENT

static __device__ __forceinline__ float sigm(float x) { return 1.0f / (1.0f + __expf(-x)); }
static __device__ __forceinline__ float tanh_f(float x) { return 1.0f - 2.0f / (__expf(2.0f * x) + 1.0f); }

// Barrier that drains ONLY LDS (lgkmcnt), leaving global loads/stores in
// flight across the barrier. Use ONLY where no cross-thread data flows
// through GLOBAL memory.
static __device__ __forceinline__ void barrier_lds() {
  asm volatile("s_waitcnt lgkmcnt(0)" ::: "memory");
  __builtin_amdgcn_sched_barrier(0);
  __builtin_amdgcn_s_barrier();
}

// ---------------------------------------------------------------------------
// Tiled fp32 GEMM (unchanged).
// ---------------------------------------------------------------------------
template<int GATHER, int BIASFIRST>
__global__ __launch_bounds__(256) void gemm_tn(
    const float* __restrict__ A, const int* __restrict__ gidx, const float* __restrict__ gtab,
    const float* __restrict__ B0, const float* __restrict__ B1, int nsplitB,
    const float* __restrict__ bias0, const float* __restrict__ bias1, int nsplitBias,
    float* __restrict__ C, int M, int N, int K)
{
  __shared__ float As[16][132];
  __shared__ float Bs[16][132];
  const int tid = threadIdx.x;
  const int m0 = blockIdx.y * 128, n0 = blockIdx.x * 128;

  const int lrow = tid >> 1;            // 0..127
  const int lk   = (tid & 1) * 8;       // 0 or 8
  const float* arow;
  if (GATHER) arow = gtab + (size_t)gidx[m0 + lrow] * K + lk;
  else        arow = A + (size_t)(m0 + lrow) * K + lk;
  const int bn = n0 + lrow;
  const float* brow = ((bn < nsplitB) ? (B0 + (size_t)bn * K)
                                      : (B1 + (size_t)(bn - nsplitB) * K)) + lk;

  const int tx = tid & 15, ty = tid >> 4;

  float bb[2][4];
#pragma unroll
  for (int in = 0; in < 2; ++in)
#pragma unroll
    for (int j = 0; j < 4; ++j) bb[in][j] = 0.f;
  if (bias0) {
#pragma unroll
    for (int in = 0; in < 2; ++in)
#pragma unroll
      for (int j = 0; j < 4; ++j) {
        int n = n0 + in * 64 + tx * 4 + j;
        bb[in][j] = (n < nsplitBias) ? bias0[n] : bias1[n - nsplitBias];
      }
  }

  float acc[2][2][4][4];
#pragma unroll
  for (int im = 0; im < 2; ++im)
#pragma unroll
    for (int in = 0; in < 2; ++in)
#pragma unroll
      for (int i = 0; i < 4; ++i)
#pragma unroll
        for (int j = 0; j < 4; ++j)
          acc[im][in][i][j] = BIASFIRST ? bb[in][j] : 0.f;

  float4 pa0 = *(const float4*)(arow);
  float4 pa1 = *(const float4*)(arow + 4);
  float4 pb0 = *(const float4*)(brow);
  float4 pb1 = *(const float4*)(brow + 4);

  int k0 = 0;
  while (true) {
    __syncthreads();
    As[lk + 0][lrow] = pa0.x; As[lk + 1][lrow] = pa0.y;
    As[lk + 2][lrow] = pa0.z; As[lk + 3][lrow] = pa0.w;
    As[lk + 4][lrow] = pa1.x; As[lk + 5][lrow] = pa1.y;
    As[lk + 6][lrow] = pa1.z; As[lk + 7][lrow] = pa1.w;
    Bs[lk + 0][lrow] = pb0.x; Bs[lk + 1][lrow] = pb0.y;
    Bs[lk + 2][lrow] = pb0.z; Bs[lk + 3][lrow] = pb0.w;
    Bs[lk + 4][lrow] = pb1.x; Bs[lk + 5][lrow] = pb1.y;
    Bs[lk + 6][lrow] = pb1.z; Bs[lk + 7][lrow] = pb1.w;
    __syncthreads();

    k0 += 16;
    const bool more = (k0 < K);
    if (more) {
      pa0 = *(const float4*)(arow + k0);
      pa1 = *(const float4*)(arow + k0 + 4);
      pb0 = *(const float4*)(brow + k0);
      pb1 = *(const float4*)(brow + k0 + 4);
    }

#pragma unroll
    for (int k = 0; k < 16; ++k) {
      const float4 av0 = *(const float4*)&As[k][ty * 4];
      const float4 av1 = *(const float4*)&As[k][64 + ty * 4];
      const float4 bv0 = *(const float4*)&Bs[k][tx * 4];
      const float4 bv1 = *(const float4*)&Bs[k][64 + tx * 4];
      const float am[2][4] = {{av0.x, av0.y, av0.z, av0.w},
                              {av1.x, av1.y, av1.z, av1.w}};
      const float bw[2][4] = {{bv0.x, bv0.y, bv0.z, bv0.w},
                              {bv1.x, bv1.y, bv1.z, bv1.w}};
#pragma unroll
      for (int im = 0; im < 2; ++im)
#pragma unroll
        for (int in = 0; in < 2; ++in)
#pragma unroll
          for (int i = 0; i < 4; ++i)
#pragma unroll
            for (int j = 0; j < 4; ++j)
              acc[im][in][i][j] += am[im][i] * bw[in][j];
    }
    if (!more) break;
  }

#pragma unroll
  for (int im = 0; im < 2; ++im)
#pragma unroll
    for (int i = 0; i < 4; ++i) {
      const int m = m0 + im * 64 + ty * 4 + i;
#pragma unroll
      for (int in = 0; in < 2; ++in) {
        float4 o;
        o.x = acc[im][in][i][0] + (BIASFIRST ? 0.f : bb[in][0]);
        o.y = acc[im][in][i][1] + (BIASFIRST ? 0.f : bb[in][1]);
        o.z = acc[im][in][i][2] + (BIASFIRST ? 0.f : bb[in][2]);
        o.w = acc[im][in][i][3] + (BIASFIRST ? 0.f : bb[in][3]);
        *(float4*)&C[(size_t)m * N + n0 + in * 64 + tx * 4] = o;
      }
    }
}

// ---------------------------------------------------------------------------
// BiLSTM recurrence: QUARTER-split (R3 winner, unchanged).
// ---------------------------------------------------------------------------
__global__ __launch_bounds__(256, 1) void lstm_esplit(
    const float* __restrict__ Xg,
    const float* __restrict__ Whh_f, const float* __restrict__ Whh_b,
    unsigned long long* __restrict__ hxbuf,  // [2 parity][64 chain][256] qwords
    float* __restrict__ blstm)
{
  const int tid = threadIdx.x;
  const int pid = blockIdx.x;
  const int q = pid >> 6, chain = pid & 63;   // quarter q owns elems [q*64, q*64+64)
  const int d = chain >> 5, b = chain & 31;
  const int j = tid & 63;               // element within own quarter
  const int g = tid >> 6;               // gate 0=i,1=f,2=g,3=o
  const int elem = q * 64 + j;          // element 0..255
  const int grow = g * 256 + elem;      // global gate row 0..1023

  const float* W = (d ? Whh_b : Whh_f) + (size_t)grow * 256;
  float4 w4[64];
#pragma unroll
  for (int i = 0; i < 64; ++i) w4[i] = *(const float4*)(W + 4 * i);

  __shared__ float h_lds[HIDN];
  __shared__ float gsL[256];
  float creg = 0.f;                     // cell for element `elem` (threads tid<64)
  h_lds[tid] = 0.f;                     // 256 threads cover HIDN=256
  __syncthreads();

  const float4* h4 = (const float4*)h_lds;
  const int pe = (tid < q * 64) ? tid : (tid + 64);
  const size_t xgoff = (size_t)d * 1024 + grow;

  for (int it = 0; it < SEQB; ++it) {
    const int t = d ? (SEQB - 1 - it) : it;
    const size_t m = (size_t)t * BATCH + b;
    const float xv = Xg[m * 2048 + xgoff];   // overlaps the poll below

    if (tid < 192) {
      const unsigned long long* src =
          &hxbuf[((size_t)(it & 1) * 64 + chain) * 256 + pe];
      unsigned long long qv;
      do { qv = __hip_atomic_load(src, __ATOMIC_RELAXED, SCOPE_AGENT); }
      while ((unsigned)(qv >> 32) != (unsigned)it);
      h_lds[pe] = __uint_as_float((unsigned)qv);
    }
    barrier_lds();

    float a0 = 0.f, a1 = 0.f, a2 = 0.f, a3 = 0.f;
#pragma unroll
    for (int i = 0; i < 64; ++i) {
      const float4 hv = h4[i];               // wave-uniform -> LDS broadcast
      const float4 wv = w4[i];
      a0 += wv.x * hv.x; a1 += wv.y * hv.y; a2 += wv.z * hv.z; a3 += wv.w * hv.w;
    }
    gsL[tid] = (a0 + a1) + (a2 + a3) + xv;   // row tid = g*64 + j
    barrier_lds();

    if (tid < 64) {
      const float gi = gsL[tid], gf = gsL[64 + tid];
      const float gg = gsL[128 + tid], go = gsL[192 + tid];
      creg = sigm(gf) * creg + sigm(gi) * tanh_f(gg);
      const float hn = sigm(go) * tanh_f(creg);
      h_lds[elem] = hn;
      const unsigned long long pk =
          ((unsigned long long)(unsigned)(it + 1) << 32) |
          (unsigned long long)__float_as_uint(hn);
      __hip_atomic_store(&hxbuf[((size_t)((it + 1) & 1) * 64 + chain) * 256 + elem], pk,
                         __ATOMIC_RELAXED, SCOPE_AGENT);
      blstm[m * HH2 + (size_t)d * HIDN + elem] = hn;
    }
    barrier_lds();
  }
}

// ---------------------------------------------------------------------------
__global__ __launch_bounds__(256) void attn_k(const float* __restrict__ blstm,
                                              const float* __restrict__ attn_w,
                                              const float* __restrict__ attn_b,
                                              float* __restrict__ attnv)
{
  const int tid = threadIdx.x;
  const int p = blockIdx.x * 4 + (tid >> 6);
  const int lane = tid & 63;
  const size_t base = (size_t)p * HH2 + lane * 8;
  float4 v0 = *(const float4*)&blstm[base];
  float4 v1 = *(const float4*)&blstm[base + 4];
  float4 w0 = *(const float4*)&attn_w[lane * 8];
  float4 w1 = *(const float4*)&attn_w[lane * 8 + 4];
  float acc = v0.x * w0.x + v0.y * w0.y + v0.z * w0.z + v0.w * w0.w
            + v1.x * w1.x + v1.y * w1.y + v1.z * w1.z + v1.w * w1.w;
#pragma unroll
  for (int off = 32; off > 0; off >>= 1) acc += __shfl_down(acc, off);
  if (lane == 0) attnv[p] = acc + attn_b[0];
}

// ---------------------------------------------------------------------------
__global__ __launch_bounds__(64) void entity_prep(const int* __restrict__ spans,
                                                  const float* __restrict__ attnv,
                                                  const float* __restrict__ blstm,
                                                  float* __restrict__ Hent,
                                                  float* __restrict__ P_out)
{
  const int nb = blockIdx.x;
  const int n = nb >> 5, b = nb & 31;
  const int tid = threadIdx.x;
  __shared__ float sc[8];
  if (tid < 8) sc[tid] = attnv[spans[n * 8 + tid] * BATCH + b];
  __syncthreads();
  float mx = sc[0];
#pragma unroll
  for (int w = 1; w < 8; ++w) mx = fmaxf(mx, sc[w]);
  float ex[8]; float ssum = 0.f;
#pragma unroll
  for (int w = 0; w < 8; ++w) { ex[w] = __expf(sc[w] - mx); ssum += ex[w]; }
  float wsum = 0.f;
#pragma unroll
  for (int w = 0; w < 8; ++w) wsum += ex[w] / ssum;
  const size_t base = ((size_t)n * BATCH + b) * HH2;
#pragma unroll
  for (int q = 0; q < 2; ++q) {
    int j = q * 256 + tid * 4;
    float4 v = *(const float4*)&blstm[base + j];
    v.x *= wsum; v.y *= wsum; v.z *= wsum; v.w *= wsum;
    *(float4*)&Hent[base + j] = v;
  }
  if (tid == 0) {
    P_out[((size_t)b * NNODE + n) * 2 + 0] = 0.001f;
    P_out[((size_t)b * NNODE + n) * 2 + 1] = 0.999f;
  }
}

// ---------------------------------------------------------------------------
__global__ void pack_ucat(const float* __restrict__ U_ioc, const float* __restrict__ Uf,
                          float* __restrict__ Ucat)
{
  int j = blockIdx.x, tid = threadIdx.x;
  for (int k = tid; k < 512; k += 128) {
    float v;
    if (j < 1536)      v = U_ioc[(size_t)j * 1024 + k];
    else if (j < 3072) v = U_ioc[(size_t)(j - 1536) * 1024 + 512 + k];
    else               v = Uf[(size_t)(j - 3072) * 512 + k];
    Ucat[(size_t)j * 512 + k] = v;
  }
}

// ---------------------------------------------------------------------------
__global__ __launch_bounds__(256) void mprep(const float* __restrict__ W1,
                                             const float* __restrict__ b1,
                                             const float* __restrict__ W2,
                                             const float* __restrict__ b2,
                                             float* __restrict__ Mmat,
                                             float* __restrict__ mbv)
{
  const int tid = threadIdx.x;
  for (int j = tid; j < 512; j += 256) {
    float a0 = 0.f, a1 = 0.f;
    for (int m = 0; m < 1024; ++m) {
      float w = W1[(size_t)m * 512 + j];
      a0 += W2[m] * w;
      a1 += W2[1024 + m] * w;
    }
    Mmat[j] = a0; Mmat[512 + j] = a1;
  }
  if (tid < 2) {
    float a = b2[tid];
    for (int m = 0; m < 1024; ++m) a += W2[tid * 1024 + m] * b1[m];
    mbv[tid] = a;
  }
}

// ---------------------------------------------------------------------------
// DAG-LSTM sequential kernel. R7 = R6 + WAVE-LOCAL slow path:
//  - master slow path has NO block barriers: each wave polls the 8 arrive
//    group-counters itself (lanes 0-7 for arg0, 8-15 for arg1; divergent
//    loop exit = all pollers satisfied), does a wave-level acquire fence,
//    lane0 updates confL + ordered-event cascade PER-WAVE (DS in-order,
//    all waves compute identical state - same replication argument as the
//    proven pstL scheme), then issues its own Tall loads immediately.
//    Divergent pfok across waves is safe: no block barrier in the path,
//    and every cond step still converges at its one block barrier.
//  - helpers: per-wave release arrive-adds (threshold 112 = 14 helpers x
//    8 waves) replace the trailing __syncthreads; the top-of-loop barrier
//    already protects sslot reuse.
// ---------------------------------------------------------------------------
__global__ __launch_bounds__(512) void dag_seq(
    const int* __restrict__ S, const int* __restrict__ T, const int* __restrict__ EN,
    const int* __restrict__ entsz,
    const float* __restrict__ WE,
    const float* __restrict__ Mmat, const float* __restrict__ mbv,
    float* __restrict__ Tall, float* __restrict__ hbuf,
    uint32_t* slotbase, uint32_t* arrive,
    const float* __restrict__ Ucat, float* __restrict__ P_out)
{
  const int tid = threadIdx.x;
  __shared__ int   SL[NSt * BATCH * 2];
  __shared__ int   TLt[NSt * BATCH];
  __shared__ int   ELt[NSt * BATCH];
  __shared__ int   eszL[BATCH];
  __shared__ float MmatL[1024];
  __shared__ float mbvL[2];
  __shared__ float pstL[NNODE];
  __shared__ int   evtofL[NSt];
  __shared__ int   confL[NSt];
  __shared__ float red0[2][8], red1[2][8];
  __shared__ uint32_t sslot;

  if (blockIdx.x < NHELP) {
    const int w = blockIdx.x;
    const int row = w * 32 + (tid >> 4);
    const int ks = (tid & 15) * 32;
    float wreg[32];
#pragma unroll
    for (int i = 0; i < 8; ++i) {
      float4 v = *(const float4*)&Ucat[(size_t)row * 512 + ks + i * 4];
      wreg[i * 4 + 0] = v.x; wreg[i * 4 + 1] = v.y; wreg[i * 4 + 2] = v.z; wreg[i * 4 + 3] = v.w;
    }
    uint32_t done = 0;
    const int g = w & 7;
    while (true) {
      if (tid == 0) {
        uint32_t sv;
        while ((sv = __hip_atomic_load(&slotbase[done], __ATOMIC_RELAXED, SCOPE_AGENT)) == 0u) {
          __builtin_amdgcn_s_sleep(1);
        }
        __builtin_amdgcn_fence(__ATOMIC_ACQUIRE, "agent");
        sslot = sv;
      }
      __syncthreads();    // publishes sslot; also protects its reuse next iter
      const uint32_t slot = sslot;
      if (slot == TERMEVT) break;
      const float* hv = hbuf + (size_t)done * HH2 + ks;
      float acc = 0.f;
#pragma unroll
      for (int i = 0; i < 8; ++i) {
        float4 v = *(const float4*)&hv[i * 4];
        acc += wreg[i * 4 + 0] * v.x + wreg[i * 4 + 1] * v.y
             + wreg[i * 4 + 2] * v.z + wreg[i * 4 + 3] * v.w;
      }
      acc += __shfl_down(acc, 8);
      acc += __shfl_down(acc, 4);
      acc += __shfl_down(acc, 2);
      acc += __shfl_down(acc, 1);
      if ((tid & 15) == 0) {
        __hip_atomic_store(&Tall[(size_t)slot + row], acc, __ATOMIC_RELAXED, SCOPE_AGENT);
      }
      // per-wave release add: orders this wave's Tall stores; no barrier.
      if ((tid & 63) == 0) {
        __hip_atomic_fetch_add(&arrive[done * 8 + g], 1u, __ATOMIC_RELEASE, SCOPE_AGENT);
      }
      ++done;
    }
    return;
  }

  // master
  for (int i = tid; i < NSt * BATCH * 2; i += 512) SL[i] = S[i];
  for (int i = tid; i < NSt * BATCH; i += 512) { TLt[i] = T[i]; ELt[i] = EN[i]; }
  for (int i = tid; i < 1024; i += 512) MmatL[i] = Mmat[i];
  if (tid < BATCH) eszL[tid] = entsz[tid];
  if (tid < 2) mbvL[tid] = mbv[tid];
  __syncthreads();

  float c = 0.f;
  uint32_t e = 0;
  for (int b = 0; b < BATCH; ++b) {
    barrier_lds();    // laggard waves must finish reading pstL before re-init
    const int esz = eszL[b];
    for (int j = tid; j < NNODE; j += 512) pstL[j] = (j < NEnt) ? 0.999f : 0.f;
    if (tid < NSt) { confL[tid] = 0; evtofL[tid] = -1; }
    __syncthreads();
    int fp = 0;       // fast-step parity for red[] double-buffer

    bool  pfok = false;
    float pt0 = 0.f, pt1 = 0.f, pt2 = 0.f, pt3 = 0.f, pt4 = 0.f, pt5 = 0.f, pt6 = 0.f, pt7 = 0.f;
    float pw0 = 0.f, pw1 = 0.f, pw2 = 0.f, pwf = 0.f;

#define PFETCH(sn)                                                              \
    do {                                                                        \
      pfok = false;                                                             \
      if ((sn) < NSt) {                                                         \
        const int sbn_ = (sn) * BATCH + b;                                      \
        const int na0_ = SL[2 * sbn_], na1_ = SL[2 * sbn_ + 1];                 \
        const int nel_ = ELt[sbn_];                                             \
        if (nel_ >= 0) {                                                        \
          const float* nwe_ = WE + (size_t)nel_ * 2048;                         \
          pw0 = nwe_[tid]; pw1 = nwe_[512 + tid]; pw2 = nwe_[1024 + tid];       \
          pwf = nwe_[1536 + tid];                                               \
        }                                                                       \
        const bool ok0_ = (na0_ < NEnt) || (confL[na0_ - NEnt] != 0);           \
        const bool ok1_ = (na1_ < NEnt) || (confL[na1_ - NEnt] != 0);           \
        if (ok0_ && ok1_) {                                                     \
          const size_t ns0_ = ((size_t)na0_ * BATCH + b) * NROWS;               \
          const size_t ns1_ = ((size_t)na1_ * BATCH + b) * NROWS;               \
          pt0 = Tall[ns0_ + tid];               pt1 = Tall[ns1_ + 1536 + tid];  \
          pt2 = Tall[ns0_ + 512 + tid];         pt3 = Tall[ns1_ + 2048 + tid];  \
          pt4 = Tall[ns0_ + 1024 + tid];        pt5 = Tall[ns1_ + 2560 + tid];  \
          pt6 = Tall[ns0_ + 3072 + tid];        pt7 = Tall[ns1_ + 3072 + tid];  \
          pfok = true;                                                          \
        }                                                                       \
      }                                                                         \
    } while (0)

    PFETCH(0);

    for (int s = 0; s < NSt; ++s) {
      const int sb = s * BATCH + b;
      const int a0 = SL[2 * sb], a1 = SL[2 * sb + 1];
      const int tgt = TLt[sb], el = ELt[sb];
      const bool valid = (tgt >= esz) && (el > -1);
      const float pa0 = pstL[a0], pa1 = pstL[a1];
      const bool cond = valid && (pa0 > 0.5f) && (pa1 > 0.5f);
      if (cond) {
        if (!pfok) {
          const int r0 = (a0 >= NEnt) ? (a0 - NEnt) : -1;
          const int r1 = (a1 >= NEnt) ? (a1 - NEnt) : -1;
          const int lane = tid & 63;
          // need flags are wave-uniform (confL read broadcasts).
          const bool need0 = (r0 >= 0) && (confL[r0] == 0);
          const bool need1 = (r1 >= 0) && (confL[r1] == 0);
          if (need0 || need1) {
            if (lane < 8 && need0) {
              const uint32_t ev = (uint32_t)evtofL[r0];
              while (__hip_atomic_load(&arrive[ev * 8 + lane], __ATOMIC_RELAXED, SCOPE_AGENT)
                     < (uint32_t)HPW) { __builtin_amdgcn_s_sleep(1); }
            }
            if (lane >= 8 && lane < 16 && need1) {
              const uint32_t ev = (uint32_t)evtofL[r1];
              while (__hip_atomic_load(&arrive[ev * 8 + (lane - 8)], __ATOMIC_RELAXED, SCOPE_AGENT)
                     < (uint32_t)HPW) { __builtin_amdgcn_s_sleep(1); }
            }
            // wave proceeds only when all its pollers exited (exec-mask loop)
            __builtin_amdgcn_fence(__ATOMIC_ACQUIRE, "agent");
            if (lane == 0) {
              // per-wave confL update + ordered-event cascade (DS in-order;
              // every wave computes the identical state).
              int evm = -1;
              if (need0) { confL[r0] = 1; if (evtofL[r0] > evm) evm = evtofL[r0]; }
              if (need1) { confL[r1] = 1; if (evtofL[r1] > evm) evm = evtofL[r1]; }
              if (evm >= 0) {
                for (int r = 0; r < 32; ++r) {
                  const int ev_ = evtofL[r];
                  if (ev_ >= 0 && ev_ <= evm) confL[r] = 1;
                }
              }
            }
          }
          const size_t s0 = ((size_t)a0 * BATCH + b) * NROWS;
          const size_t s1 = ((size_t)a1 * BATCH + b) * NROWS;
          pt0 = Tall[s0 + tid];        pt1 = Tall[s1 + 1536 + tid];
          pt2 = Tall[s0 + 512 + tid];  pt3 = Tall[s1 + 2048 + tid];
          pt4 = Tall[s0 + 1024 + tid]; pt5 = Tall[s1 + 2560 + tid];
          pt6 = Tall[s0 + 3072 + tid]; pt7 = Tall[s1 + 3072 + tid];
        }
        const float ii = pw0 + pt0 + pt1;
        const float oo = pw1 + pt2 + pt3;
        const float ch = pw2 + pt4 + pt5;
        const float f0g = sigm(pwf + pt6);
        const float f1g = sigm(pwf + pt7);
        PFETCH(s + 1);
        float cn = (f0g + f1g) * c + sigm(ii) * tanh_f(ch);
        cn = fminf(fmaxf(cn, -100.f), 100.f);
        float hh = sigm(oo) * tanh_f(cn);
        hh = fminf(fmaxf(hh, -100.f), 100.f);
        const bool pubc = (tgt < NEnt + 32);   // publish regardless of o1
        if (pubc) {
          __hip_atomic_store(&hbuf[(size_t)e * HH2 + tid], hh, __ATOMIC_RELAXED, SCOPE_AGENT);
        }
        float l0 = MmatL[tid] * hh, l1 = MmatL[512 + tid] * hh;
#pragma unroll
        for (int off = 32; off > 0; off >>= 1) {
          l0 += __shfl_down(l0, off);
          l1 += __shfl_down(l1, off);
        }
        if ((tid & 63) == 0) { red0[fp][tid >> 6] = l0; red1[fp][tid >> 6] = l1; }
        if (pubc) {
          __syncthreads();   // combined: drains hbuf stores + publishes red
          if (tid == 0) {
            evtofL[tgt - NEnt] = (int)e;
            // EARLY release (before softmax): helpers overlap the master's
            // softmax + next-step gate math.
            __hip_atomic_store(&slotbase[e],
                               (uint32_t)(((uint32_t)tgt * BATCH + (uint32_t)b) * NROWS),
                               __ATOMIC_RELEASE, SCOPE_AGENT);
          }
        } else {
          barrier_lds();
        }
        // redundant softmax: identical FP ops on identical LDS inputs in
        // every thread -> bit-identical o0/o1 everywhere.
        float L0 = mbvL[0], L1 = mbvL[1];
#pragma unroll
        for (int wv = 0; wv < 8; ++wv) { L0 += red0[fp][wv]; L1 += red1[fp][wv]; }
        const float mx = fmaxf(L0, L1);
        const float e0 = __expf(L0 - mx), e1 = __expf(L1 - mx);
        const float inv = 1.f / (e0 + e1);
        const float o0 = e0 * inv, o1 = e1 * inv;
        if ((tid & 63) == 0) pstL[tgt] = o1;   // per-wave write: DS in-order
        if (tid == 0) {
          P_out[((size_t)b * NNODE + tgt) * 2 + 0] = o0;
          P_out[((size_t)b * NNODE + tgt) * 2 + 1] = o1;
        }
        fp ^= 1;
        c = cn;
        if (pubc) {
          ++e;
          barrier_lds();     // evtofL visible before any later slow-path read
        }
      } else {
        PFETCH(s + 1);
        if (tid == 0 && (valid || tgt >= NEnt)) {
          const float o0 = valid ? 0.999f : ((tgt < NEnt) ? 0.001f : 0.f);
          const float o1 = valid ? 0.001f : ((tgt < NEnt) ? 0.999f : 0.f);
          P_out[((size_t)b * NNODE + tgt) * 2 + 0] = o0;
          P_out[((size_t)b * NNODE + tgt) * 2 + 1] = o1;
        }
        if (valid && (tid & 63) == 0) pstL[tgt] = 0.001f;
        // no barrier: all waves wrote the identical value themselves.
      }
    }
#undef PFETCH
  }
  if (tid == 0) {
    __hip_atomic_store(&slotbase[e], TERMEVT, __ATOMIC_RELEASE, SCOPE_AGENT);
  }
}

// ---------------------------------------------------------------------------
extern "C" void kernel_launch(void* const* d_in, const int* in_sizes, int n_in,
                              void* d_out, int out_size, void* d_ws, size_t ws_size,
                              hipStream_t stream)
{
  const int* tokens = (const int*)d_in[0];
  const int* spans  = (const int*)d_in[1];
  const int* enames = (const int*)d_in[2];
  const int* T      = (const int*)d_in[5];
  const int* S      = (const int*)d_in[6];
  const int* entsz  = (const int*)d_in[7];
  const float* word_emb = (const float*)d_in[8];
  const float* elem_emb = (const float*)d_in[9];
  const float* attn_w = (const float*)d_in[10];
  const float* attn_b = (const float*)d_in[11];
  const float* Wih_f = (const float*)d_in[12];
  const float* Whh_f = (const float*)d_in[13];
  const float* bl_f  = (const float*)d_in[14];
  const float* Wih_b = (const float*)d_in[15];
  const float* Whh_b = (const float*)d_in[16];
  const float* bl_b  = (const float*)d_in[17];
  const float* W_ioc = (const float*)d_in[18];
  const float* U_ioc = (const float*)d_in[19];
  const float* b_ioc = (const float*)d_in[20];
  const float* Wf    = (const float*)d_in[21];
  const float* Uf    = (const float*)d_in[22];
  const float* bf    = (const float*)d_in[23];
  const float* W1    = (const float*)d_in[24];
  const float* b1    = (const float*)d_in[25];
  const float* W2    = (const float*)d_in[26];
  const float* b2    = (const float*)d_in[27];
  float* P_out = (float*)d_out;

  char* ws = (char*)d_ws;
  uint32_t* slotbase = (uint32_t*)(ws + 8192);           // 2048 u32 capacity
  uint32_t* arrive   = (uint32_t*)(ws + 16384);          // 8*1024 u32 = 32KB
  float* fws = (float*)(ws + 65536);
  size_t off = 0;
  float* Xg    = fws + off; off += (size_t)16384 * 2048;
  float* blstm = fws + off; off += (size_t)SEQB * BATCH * HH2;
  float* attnv = fws + off; off += (size_t)SEQB * BATCH;
  float* Hent  = fws + off; off += (size_t)2048 * 512;
  float* Tall  = fws + off; off += (size_t)96 * BATCH * NROWS;
  unsigned long long* hxbuf = (unsigned long long*)(fws + off);
  off += (size_t)2 * 64 * 256 * 2;           // qwords = 2 floats each
  float* Ucat  = fws + off; off += (size_t)NROWS * 512;
  float* WE    = fws + off; off += (size_t)128 * 2048;   // [el][1536 ioc | 512 f]
  float* Mmat  = fws + off; off += 1024;
  float* mbv   = fws + off; off += 16;
  float* hbuf  = fws + off; off += (size_t)1024 * 512;
  const size_t needed = 65536 + off * sizeof(float);
  if (ws_size < needed) return;   // workspace too small: bail (visible failure)

  hipMemsetAsync(d_ws, 0, 65536, stream);    // slotbase=0 (poll sentinel), arrive=0
  // hxbuf must start as tag=0/value=0 (valid "h=0 at step 0" records)
  hipMemsetAsync(hxbuf, 0, (size_t)2 * 64 * 256 * 8, stream);

  // 1) Xg = gather(word_emb, tokens) @ [Wih_f;Wih_b].T + [bl_f;bl_b]
  gemm_tn<1, 0><<<dim3(2048 / 128, 16384 / 128), 256, 0, stream>>>(
      nullptr, tokens, word_emb, Wih_f, Wih_b, 1024, bl_f, bl_b, 1024,
      Xg, 16384, 2048, 256);

  // 2) recurrent BiLSTM (quarter-split, tagged h exchange, resident weights)
  lstm_esplit<<<256, 256, 0, stream>>>(Xg, Whh_f, Whh_b, hxbuf, blstm);

  // 3) attention scores + entity H
  attn_k<<<4096, 256, 0, stream>>>(blstm, attn_w, attn_b, attnv);
  entity_prep<<<2048, 64, 0, stream>>>(spans, attnv, blstm, Hent, P_out);

  // 4) DAG-LSTM precompute
  pack_ucat<<<NROWS, 128, 0, stream>>>(U_ioc, Uf, Ucat);
  // WE[el] = [b_ioc + elem_emb[el] @ W_ioc.T | bf + elem_emb[el] @ Wf.T]
  gemm_tn<0, 1><<<dim3(2048 / 128, 1), 256, 0, stream>>>(
      elem_emb, nullptr, nullptr, W_ioc, Wf, 1536, b_ioc, bf, 1536,
      WE, 128, 2048, 128);
  mprep<<<1, 256, 0, stream>>>(W1, b1, W2, b2, Mmat, mbv);
  gemm_tn<0, 0><<<dim3(NROWS / 128, 2048 / 128), 256, 0, stream>>>(
      Hent, nullptr, nullptr, Ucat, nullptr, 0x40000000, nullptr, nullptr, 0,
      Tall, 2048, NROWS, 512);

  // 5) sequential DAG-LSTM with helper projection grid
  dag_seq<<<NHELP + 1, 512, 0, stream>>>(S, T, enames, entsz, WE, Mmat, mbv,
                                         Tall, hbuf, slotbase, arrive, Ucat, P_out);
}

// Round 9
// 5156.710 us; speedup vs baseline: 1.8331x; 1.8331x over previous
//
#include <hip/hip_runtime.h>
#include <stdint.h>

#define SEQB 512
#define BATCH 32
#define EDIM 256
#define HIDN 256
#define HH2 512
#define RDIM 128
#define NEnt 64
#define NSt 64
#define NNODE 128
#define NHELP 112
#define NROWS 3584      // 1536 (U0) + 1536 (U1) + 512 (Uf)
#define TERMEVT 0xFFFFFFFFu
#define SENTU 0x7F7F7F7Fu   // 3.39e38; helper outputs bounded ~2.5e3 -> impossible
#define SCOPE_AGENT __HIP_MEMORY_SCOPE_AGENT

static __device__ __forceinline__ float sigm(float x) { return 1.0f / (1.0f + __expf(-x)); }
static __device__ __forceinline__ float tanh_f(float x) { return 1.0f - 2.0f / (__expf(2.0f * x) + 1.0f); }

// Barrier that drains ONLY LDS (lgkmcnt), leaving global loads/stores in
// flight across the barrier. Use ONLY where no cross-thread data flows
// through GLOBAL memory.
static __device__ __forceinline__ void barrier_lds() {
  asm volatile("s_waitcnt lgkmcnt(0)" ::: "memory");
  __builtin_amdgcn_sched_barrier(0);
  __builtin_amdgcn_s_barrier();
}

// ---------------------------------------------------------------------------
// Tiled fp32 GEMM (unchanged).
// ---------------------------------------------------------------------------
template<int GATHER, int BIASFIRST>
__global__ __launch_bounds__(256) void gemm_tn(
    const float* __restrict__ A, const int* __restrict__ gidx, const float* __restrict__ gtab,
    const float* __restrict__ B0, const float* __restrict__ B1, int nsplitB,
    const float* __restrict__ bias0, const float* __restrict__ bias1, int nsplitBias,
    float* __restrict__ C, int M, int N, int K)
{
  __shared__ float As[16][132];
  __shared__ float Bs[16][132];
  const int tid = threadIdx.x;
  const int m0 = blockIdx.y * 128, n0 = blockIdx.x * 128;

  const int lrow = tid >> 1;            // 0..127
  const int lk   = (tid & 1) * 8;       // 0 or 8
  const float* arow;
  if (GATHER) arow = gtab + (size_t)gidx[m0 + lrow] * K + lk;
  else        arow = A + (size_t)(m0 + lrow) * K + lk;
  const int bn = n0 + lrow;
  const float* brow = ((bn < nsplitB) ? (B0 + (size_t)bn * K)
                                      : (B1 + (size_t)(bn - nsplitB) * K)) + lk;

  const int tx = tid & 15, ty = tid >> 4;

  float bb[2][4];
#pragma unroll
  for (int in = 0; in < 2; ++in)
#pragma unroll
    for (int j = 0; j < 4; ++j) bb[in][j] = 0.f;
  if (bias0) {
#pragma unroll
    for (int in = 0; in < 2; ++in)
#pragma unroll
      for (int j = 0; j < 4; ++j) {
        int n = n0 + in * 64 + tx * 4 + j;
        bb[in][j] = (n < nsplitBias) ? bias0[n] : bias1[n - nsplitBias];
      }
  }

  float acc[2][2][4][4];
#pragma unroll
  for (int im = 0; im < 2; ++im)
#pragma unroll
    for (int in = 0; in < 2; ++in)
#pragma unroll
      for (int i = 0; i < 4; ++i)
#pragma unroll
        for (int j = 0; j < 4; ++j)
          acc[im][in][i][j] = BIASFIRST ? bb[in][j] : 0.f;

  float4 pa0 = *(const float4*)(arow);
  float4 pa1 = *(const float4*)(arow + 4);
  float4 pb0 = *(const float4*)(brow);
  float4 pb1 = *(const float4*)(brow + 4);

  int k0 = 0;
  while (true) {
    __syncthreads();
    As[lk + 0][lrow] = pa0.x; As[lk + 1][lrow] = pa0.y;
    As[lk + 2][lrow] = pa0.z; As[lk + 3][lrow] = pa0.w;
    As[lk + 4][lrow] = pa1.x; As[lk + 5][lrow] = pa1.y;
    As[lk + 6][lrow] = pa1.z; As[lk + 7][lrow] = pa1.w;
    Bs[lk + 0][lrow] = pb0.x; Bs[lk + 1][lrow] = pb0.y;
    Bs[lk + 2][lrow] = pb0.z; Bs[lk + 3][lrow] = pb0.w;
    Bs[lk + 4][lrow] = pb1.x; Bs[lk + 5][lrow] = pb1.y;
    Bs[lk + 6][lrow] = pb1.z; Bs[lk + 7][lrow] = pb1.w;
    __syncthreads();

    k0 += 16;
    const bool more = (k0 < K);
    if (more) {
      pa0 = *(const float4*)(arow + k0);
      pa1 = *(const float4*)(arow + k0 + 4);
      pb0 = *(const float4*)(brow + k0);
      pb1 = *(const float4*)(brow + k0 + 4);
    }

#pragma unroll
    for (int k = 0; k < 16; ++k) {
      const float4 av0 = *(const float4*)&As[k][ty * 4];
      const float4 av1 = *(const float4*)&As[k][64 + ty * 4];
      const float4 bv0 = *(const float4*)&Bs[k][tx * 4];
      const float4 bv1 = *(const float4*)&Bs[k][64 + tx * 4];
      const float am[2][4] = {{av0.x, av0.y, av0.z, av0.w},
                              {av1.x, av1.y, av1.z, av1.w}};
      const float bw[2][4] = {{bv0.x, bv0.y, bv0.z, bv0.w},
                              {bv1.x, bv1.y, bv1.z, bv1.w}};
#pragma unroll
      for (int im = 0; im < 2; ++im)
#pragma unroll
        for (int in = 0; in < 2; ++in)
#pragma unroll
          for (int i = 0; i < 4; ++i)
#pragma unroll
            for (int j = 0; j < 4; ++j)
              acc[im][in][i][j] += am[im][i] * bw[in][j];
    }
    if (!more) break;
  }

#pragma unroll
  for (int im = 0; im < 2; ++im)
#pragma unroll
    for (int i = 0; i < 4; ++i) {
      const int m = m0 + im * 64 + ty * 4 + i;
#pragma unroll
      for (int in = 0; in < 2; ++in) {
        float4 o;
        o.x = acc[im][in][i][0] + (BIASFIRST ? 0.f : bb[in][0]);
        o.y = acc[im][in][i][1] + (BIASFIRST ? 0.f : bb[in][1]);
        o.z = acc[im][in][i][2] + (BIASFIRST ? 0.f : bb[in][2]);
        o.w = acc[im][in][i][3] + (BIASFIRST ? 0.f : bb[in][3]);
        *(float4*)&C[(size_t)m * N + n0 + in * 64 + tx * 4] = o;
      }
    }
}

// ---------------------------------------------------------------------------
// BiLSTM recurrence: QUARTER-split (R3 winner, unchanged).
// ---------------------------------------------------------------------------
__global__ __launch_bounds__(256, 1) void lstm_esplit(
    const float* __restrict__ Xg,
    const float* __restrict__ Whh_f, const float* __restrict__ Whh_b,
    unsigned long long* __restrict__ hxbuf,  // [2 parity][64 chain][256] qwords
    float* __restrict__ blstm)
{
  const int tid = threadIdx.x;
  const int pid = blockIdx.x;
  const int q = pid >> 6, chain = pid & 63;   // quarter q owns elems [q*64, q*64+64)
  const int d = chain >> 5, b = chain & 31;
  const int j = tid & 63;               // element within own quarter
  const int g = tid >> 6;               // gate 0=i,1=f,2=g,3=o
  const int elem = q * 64 + j;          // element 0..255
  const int grow = g * 256 + elem;      // global gate row 0..1023

  const float* W = (d ? Whh_b : Whh_f) + (size_t)grow * 256;
  float4 w4[64];
#pragma unroll
  for (int i = 0; i < 64; ++i) w4[i] = *(const float4*)(W + 4 * i);

  __shared__ float h_lds[HIDN];
  __shared__ float gsL[256];
  float creg = 0.f;                     // cell for element `elem` (threads tid<64)
  h_lds[tid] = 0.f;                     // 256 threads cover HIDN=256
  __syncthreads();

  const float4* h4 = (const float4*)h_lds;
  const int pe = (tid < q * 64) ? tid : (tid + 64);
  const size_t xgoff = (size_t)d * 1024 + grow;

  for (int it = 0; it < SEQB; ++it) {
    const int t = d ? (SEQB - 1 - it) : it;
    const size_t m = (size_t)t * BATCH + b;
    const float xv = Xg[m * 2048 + xgoff];   // overlaps the poll below

    if (tid < 192) {
      const unsigned long long* src =
          &hxbuf[((size_t)(it & 1) * 64 + chain) * 256 + pe];
      unsigned long long qv;
      do { qv = __hip_atomic_load(src, __ATOMIC_RELAXED, SCOPE_AGENT); }
      while ((unsigned)(qv >> 32) != (unsigned)it);
      h_lds[pe] = __uint_as_float((unsigned)qv);
    }
    barrier_lds();

    float a0 = 0.f, a1 = 0.f, a2 = 0.f, a3 = 0.f;
#pragma unroll
    for (int i = 0; i < 64; ++i) {
      const float4 hv = h4[i];               // wave-uniform -> LDS broadcast
      const float4 wv = w4[i];
      a0 += wv.x * hv.x; a1 += wv.y * hv.y; a2 += wv.z * hv.z; a3 += wv.w * hv.w;
    }
    gsL[tid] = (a0 + a1) + (a2 + a3) + xv;   // row tid = g*64 + j
    barrier_lds();

    if (tid < 64) {
      const float gi = gsL[tid], gf = gsL[64 + tid];
      const float gg = gsL[128 + tid], go = gsL[192 + tid];
      creg = sigm(gf) * creg + sigm(gi) * tanh_f(gg);
      const float hn = sigm(go) * tanh_f(creg);
      h_lds[elem] = hn;
      const unsigned long long pk =
          ((unsigned long long)(unsigned)(it + 1) << 32) |
          (unsigned long long)__float_as_uint(hn);
      __hip_atomic_store(&hxbuf[((size_t)((it + 1) & 1) * 64 + chain) * 256 + elem], pk,
                         __ATOMIC_RELAXED, SCOPE_AGENT);
      blstm[m * HH2 + (size_t)d * HIDN + elem] = hn;
    }
    barrier_lds();
  }
}

// ---------------------------------------------------------------------------
__global__ __launch_bounds__(256) void attn_k(const float* __restrict__ blstm,
                                              const float* __restrict__ attn_w,
                                              const float* __restrict__ attn_b,
                                              float* __restrict__ attnv)
{
  const int tid = threadIdx.x;
  const int p = blockIdx.x * 4 + (tid >> 6);
  const int lane = tid & 63;
  const size_t base = (size_t)p * HH2 + lane * 8;
  float4 v0 = *(const float4*)&blstm[base];
  float4 v1 = *(const float4*)&blstm[base + 4];
  float4 w0 = *(const float4*)&attn_w[lane * 8];
  float4 w1 = *(const float4*)&attn_w[lane * 8 + 4];
  float acc = v0.x * w0.x + v0.y * w0.y + v0.z * w0.z + v0.w * w0.w
            + v1.x * w1.x + v1.y * w1.y + v1.z * w1.z + v1.w * w1.w;
#pragma unroll
  for (int off = 32; off > 0; off >>= 1) acc += __shfl_down(acc, off);
  if (lane == 0) attnv[p] = acc + attn_b[0];
}

// ---------------------------------------------------------------------------
__global__ __launch_bounds__(64) void entity_prep(const int* __restrict__ spans,
                                                  const float* __restrict__ attnv,
                                                  const float* __restrict__ blstm,
                                                  float* __restrict__ Hent,
                                                  float* __restrict__ P_out)
{
  const int nb = blockIdx.x;
  const int n = nb >> 5, b = nb & 31;
  const int tid = threadIdx.x;
  __shared__ float sc[8];
  if (tid < 8) sc[tid] = attnv[spans[n * 8 + tid] * BATCH + b];
  __syncthreads();
  float mx = sc[0];
#pragma unroll
  for (int w = 1; w < 8; ++w) mx = fmaxf(mx, sc[w]);
  float ex[8]; float ssum = 0.f;
#pragma unroll
  for (int w = 0; w < 8; ++w) { ex[w] = __expf(sc[w] - mx); ssum += ex[w]; }
  float wsum = 0.f;
#pragma unroll
  for (int w = 0; w < 8; ++w) wsum += ex[w] / ssum;
  const size_t base = ((size_t)n * BATCH + b) * HH2;
#pragma unroll
  for (int q = 0; q < 2; ++q) {
    int j = q * 256 + tid * 4;
    float4 v = *(const float4*)&blstm[base + j];
    v.x *= wsum; v.y *= wsum; v.z *= wsum; v.w *= wsum;
    *(float4*)&Hent[base + j] = v;
  }
  if (tid == 0) {
    P_out[((size_t)b * NNODE + n) * 2 + 0] = 0.001f;
    P_out[((size_t)b * NNODE + n) * 2 + 1] = 0.999f;
  }
}

// ---------------------------------------------------------------------------
__global__ void pack_ucat(const float* __restrict__ U_ioc, const float* __restrict__ Uf,
                          float* __restrict__ Ucat)
{
  int j = blockIdx.x, tid = threadIdx.x;
  for (int k = tid; k < 512; k += 128) {
    float v;
    if (j < 1536)      v = U_ioc[(size_t)j * 1024 + k];
    else if (j < 3072) v = U_ioc[(size_t)(j - 1536) * 1024 + 512 + k];
    else               v = Uf[(size_t)(j - 3072) * 512 + k];
    Ucat[(size_t)j * 512 + k] = v;
  }
}

// ---------------------------------------------------------------------------
__global__ __launch_bounds__(256) void mprep(const float* __restrict__ W1,
                                             const float* __restrict__ b1,
                                             const float* __restrict__ W2,
                                             const float* __restrict__ b2,
                                             float* __restrict__ Mmat,
                                             float* __restrict__ mbv)
{
  const int tid = threadIdx.x;
  for (int j = tid; j < 512; j += 256) {
    float a0 = 0.f, a1 = 0.f;
    for (int m = 0; m < 1024; ++m) {
      float w = W1[(size_t)m * 512 + j];
      a0 += W2[m] * w;
      a1 += W2[1024 + m] * w;
    }
    Mmat[j] = a0; Mmat[512 + j] = a1;
  }
  if (tid < 2) {
    float a = b2[tid];
    for (int m = 0; m < 1024; ++m) a += W2[tid * 1024 + m] * b1[m];
    mbv[tid] = a;
  }
}

// ---------------------------------------------------------------------------
// DAG-LSTM sequential kernel. R8 = R6 master/helper with VALUE-AS-SIGNAL:
//  - Tall's relation region is pre-filled with sentinel 0x7F7F7F7F (3.39e38;
//    helper outputs are bounded |acc| <= ~2.5e3, so the pattern is
//    unproducible). Each (tgt,b) slice is written EXACTLY ONCE per run ->
//    monotonic single-write protocol: a cached copy is either sentinel
//    (triggers coherent re-poll) or the final value. L1-staleness safe.
//  - master: NO slow path. PFETCH always loads; at consume each thread
//    re-polls (atomic relaxed + s_sleep backoff) only its stale values.
//    No arrive, no fence, no confL/evtofL, no extra barriers.
//  - helpers: no arrive adds, no trailing barrier (sslot parity-double-
//    buffered; single top __syncthreads per event is sufficient).
//  - publish: R6 scheme (unconditional for tgt<NEnt+32, combined barrier,
//    early slotbase release; slotbase!=0 is the helper wake signal).
// ---------------------------------------------------------------------------
__global__ __launch_bounds__(512) void dag_seq(
    const int* __restrict__ S, const int* __restrict__ T, const int* __restrict__ EN,
    const int* __restrict__ entsz,
    const float* __restrict__ WE,
    const float* __restrict__ Mmat, const float* __restrict__ mbv,
    float* __restrict__ Tall, float* __restrict__ hbuf,
    uint32_t* slotbase,
    const float* __restrict__ Ucat, float* __restrict__ P_out)
{
  const int tid = threadIdx.x;
  __shared__ int   SL[NSt * BATCH * 2];
  __shared__ int   TLt[NSt * BATCH];
  __shared__ int   ELt[NSt * BATCH];
  __shared__ int   eszL[BATCH];
  __shared__ float MmatL[1024];
  __shared__ float mbvL[2];
  __shared__ float pstL[NNODE];
  __shared__ float red0[2][8], red1[2][8];
  __shared__ uint32_t sslotP[2];

  if (blockIdx.x < NHELP) {
    const int w = blockIdx.x;
    const int row = w * 32 + (tid >> 4);
    const int ks = (tid & 15) * 32;
    float wreg[32];
#pragma unroll
    for (int i = 0; i < 8; ++i) {
      float4 v = *(const float4*)&Ucat[(size_t)row * 512 + ks + i * 4];
      wreg[i * 4 + 0] = v.x; wreg[i * 4 + 1] = v.y; wreg[i * 4 + 2] = v.z; wreg[i * 4 + 3] = v.w;
    }
    uint32_t done = 0;
    while (true) {
      if (tid == 0) {
        uint32_t sv;
        while ((sv = __hip_atomic_load(&slotbase[done], __ATOMIC_RELAXED, SCOPE_AGENT)) == 0u) {
          __builtin_amdgcn_s_sleep(1);
        }
        __builtin_amdgcn_fence(__ATOMIC_ACQUIRE, "agent");
        sslotP[done & 1] = sv;
      }
      __syncthreads();   // single barrier/event; parity protects sslot reuse
      const uint32_t slot = sslotP[done & 1];
      if (slot == TERMEVT) break;
      const float* hv = hbuf + (size_t)done * HH2 + ks;
      float acc = 0.f;
#pragma unroll
      for (int i = 0; i < 8; ++i) {
        float4 v = *(const float4*)&hv[i * 4];
        acc += wreg[i * 4 + 0] * v.x + wreg[i * 4 + 1] * v.y
             + wreg[i * 4 + 2] * v.z + wreg[i * 4 + 3] * v.w;
      }
      acc += __shfl_down(acc, 8);
      acc += __shfl_down(acc, 4);
      acc += __shfl_down(acc, 2);
      acc += __shfl_down(acc, 1);
      if ((tid & 15) == 0) {
        // value IS the signal (sentinel -> final value, single write ever)
        __hip_atomic_store(&Tall[(size_t)slot + row], acc, __ATOMIC_RELAXED, SCOPE_AGENT);
      }
      ++done;
    }
    return;
  }

  // master
  for (int i = tid; i < NSt * BATCH * 2; i += 512) SL[i] = S[i];
  for (int i = tid; i < NSt * BATCH; i += 512) { TLt[i] = T[i]; ELt[i] = EN[i]; }
  for (int i = tid; i < 1024; i += 512) MmatL[i] = Mmat[i];
  if (tid < BATCH) eszL[tid] = entsz[tid];
  if (tid < 2) mbvL[tid] = mbv[tid];
  __syncthreads();

  float c = 0.f;
  uint32_t e = 0;
  for (int b = 0; b < BATCH; ++b) {
    barrier_lds();    // laggard waves must finish reading pstL before re-init
    const int esz = eszL[b];
    for (int j = tid; j < NNODE; j += 512) pstL[j] = (j < NEnt) ? 0.999f : 0.f;
    __syncthreads();
    int fp = 0;       // fast-step parity for red[] double-buffer

    float pt0 = 0.f, pt1 = 0.f, pt2 = 0.f, pt3 = 0.f, pt4 = 0.f, pt5 = 0.f, pt6 = 0.f, pt7 = 0.f;
    float pw0 = 0.f, pw1 = 0.f, pw2 = 0.f, pwf = 0.f;

// Always-prefetch (no gating): stale values carry the sentinel and are
// re-polled at consume time.
#define PFETCH(sn)                                                              \
    do {                                                                        \
      if ((sn) < NSt) {                                                         \
        const int sbn_ = (sn) * BATCH + b;                                      \
        const int na0_ = SL[2 * sbn_], na1_ = SL[2 * sbn_ + 1];                 \
        const int nel_ = ELt[sbn_];                                             \
        if (nel_ >= 0) {                                                        \
          const float* nwe_ = WE + (size_t)nel_ * 2048;                         \
          pw0 = nwe_[tid]; pw1 = nwe_[512 + tid]; pw2 = nwe_[1024 + tid];       \
          pwf = nwe_[1536 + tid];                                               \
        }                                                                       \
        const size_t ns0_ = ((size_t)na0_ * BATCH + b) * NROWS;                 \
        const size_t ns1_ = ((size_t)na1_ * BATCH + b) * NROWS;                 \
        pt0 = Tall[ns0_ + tid];               pt1 = Tall[ns1_ + 1536 + tid];    \
        pt2 = Tall[ns0_ + 512 + tid];         pt3 = Tall[ns1_ + 2048 + tid];    \
        pt4 = Tall[ns0_ + 1024 + tid];        pt5 = Tall[ns1_ + 2560 + tid];    \
        pt6 = Tall[ns0_ + 3072 + tid];        pt7 = Tall[ns1_ + 3072 + tid];    \
      }                                                                         \
    } while (0)

// Coherent re-poll of one stale value (exec-mask divergence is fine).
#define REPOLL(pt, ap)                                                          \
    do {                                                                        \
      if (__float_as_uint(pt) == SENTU) {                                       \
        do {                                                                    \
          __builtin_amdgcn_s_sleep(2);                                          \
          pt = __hip_atomic_load((ap), __ATOMIC_RELAXED, SCOPE_AGENT);          \
        } while (__float_as_uint(pt) == SENTU);                                 \
      }                                                                         \
    } while (0)

    PFETCH(0);

    for (int s = 0; s < NSt; ++s) {
      const int sb = s * BATCH + b;
      const int a0 = SL[2 * sb], a1 = SL[2 * sb + 1];
      const int tgt = TLt[sb], el = ELt[sb];
      const bool valid = (tgt >= esz) && (el > -1);
      const float pa0 = pstL[a0], pa1 = pstL[a1];
      const bool cond = valid && (pa0 > 0.5f) && (pa1 > 0.5f);
      if (cond) {
        {
          const size_t s0 = ((size_t)a0 * BATCH + b) * NROWS;
          const size_t s1 = ((size_t)a1 * BATCH + b) * NROWS;
          REPOLL(pt0, &Tall[s0 + tid]);
          REPOLL(pt2, &Tall[s0 + 512 + tid]);
          REPOLL(pt4, &Tall[s0 + 1024 + tid]);
          REPOLL(pt6, &Tall[s0 + 3072 + tid]);
          REPOLL(pt1, &Tall[s1 + 1536 + tid]);
          REPOLL(pt3, &Tall[s1 + 2048 + tid]);
          REPOLL(pt5, &Tall[s1 + 2560 + tid]);
          REPOLL(pt7, &Tall[s1 + 3072 + tid]);
        }
        const float ii = pw0 + pt0 + pt1;
        const float oo = pw1 + pt2 + pt3;
        const float ch = pw2 + pt4 + pt5;
        const float f0g = sigm(pwf + pt6);
        const float f1g = sigm(pwf + pt7);
        PFETCH(s + 1);
        float cn = (f0g + f1g) * c + sigm(ii) * tanh_f(ch);
        cn = fminf(fmaxf(cn, -100.f), 100.f);
        float hh = sigm(oo) * tanh_f(cn);
        hh = fminf(fmaxf(hh, -100.f), 100.f);
        const bool pubc = (tgt < NEnt + 32);   // publish regardless of o1
        if (pubc) {
          __hip_atomic_store(&hbuf[(size_t)e * HH2 + tid], hh, __ATOMIC_RELAXED, SCOPE_AGENT);
        }
        float l0 = MmatL[tid] * hh, l1 = MmatL[512 + tid] * hh;
#pragma unroll
        for (int off = 32; off > 0; off >>= 1) {
          l0 += __shfl_down(l0, off);
          l1 += __shfl_down(l1, off);
        }
        if ((tid & 63) == 0) { red0[fp][tid >> 6] = l0; red1[fp][tid >> 6] = l1; }
        if (pubc) {
          __syncthreads();   // combined: drains hbuf stores + publishes red
          if (tid == 0) {
            // EARLY release (before softmax): helpers overlap the master's
            // softmax + next-step gate math. slotbase!=0 is the wake signal.
            __hip_atomic_store(&slotbase[e],
                               (uint32_t)(((uint32_t)tgt * BATCH + (uint32_t)b) * NROWS),
                               __ATOMIC_RELEASE, SCOPE_AGENT);
          }
          ++e;
        } else {
          barrier_lds();
        }
        // redundant softmax: identical FP ops on identical LDS inputs in
        // every thread -> bit-identical o0/o1 everywhere.
        float L0 = mbvL[0], L1 = mbvL[1];
#pragma unroll
        for (int wv = 0; wv < 8; ++wv) { L0 += red0[fp][wv]; L1 += red1[fp][wv]; }
        const float mx = fmaxf(L0, L1);
        const float e0 = __expf(L0 - mx), e1 = __expf(L1 - mx);
        const float inv = 1.f / (e0 + e1);
        const float o0 = e0 * inv, o1 = e1 * inv;
        if ((tid & 63) == 0) pstL[tgt] = o1;   // per-wave write: DS in-order
        if (tid == 0) {
          P_out[((size_t)b * NNODE + tgt) * 2 + 0] = o0;
          P_out[((size_t)b * NNODE + tgt) * 2 + 1] = o1;
        }
        fp ^= 1;
        c = cn;
      } else {
        PFETCH(s + 1);
        if (tid == 0 && (valid || tgt >= NEnt)) {
          const float o0 = valid ? 0.999f : ((tgt < NEnt) ? 0.001f : 0.f);
          const float o1 = valid ? 0.001f : ((tgt < NEnt) ? 0.999f : 0.f);
          P_out[((size_t)b * NNODE + tgt) * 2 + 0] = o0;
          P_out[((size_t)b * NNODE + tgt) * 2 + 1] = o1;
        }
        if (valid && (tid & 63) == 0) pstL[tgt] = 0.001f;
        // no barrier: all waves wrote the identical value themselves.
      }
    }
#undef PFETCH
#undef REPOLL
  }
  if (tid == 0) {
    __hip_atomic_store(&slotbase[e], TERMEVT, __ATOMIC_RELEASE, SCOPE_AGENT);
  }
}

// ---------------------------------------------------------------------------
extern "C" void kernel_launch(void* const* d_in, const int* in_sizes, int n_in,
                              void* d_out, int out_size, void* d_ws, size_t ws_size,
                              hipStream_t stream)
{
  const int* tokens = (const int*)d_in[0];
  const int* spans  = (const int*)d_in[1];
  const int* enames = (const int*)d_in[2];
  const int* T      = (const int*)d_in[5];
  const int* S      = (const int*)d_in[6];
  const int* entsz  = (const int*)d_in[7];
  const float* word_emb = (const float*)d_in[8];
  const float* elem_emb = (const float*)d_in[9];
  const float* attn_w = (const float*)d_in[10];
  const float* attn_b = (const float*)d_in[11];
  const float* Wih_f = (const float*)d_in[12];
  const float* Whh_f = (const float*)d_in[13];
  const float* bl_f  = (const float*)d_in[14];
  const float* Wih_b = (const float*)d_in[15];
  const float* Whh_b = (const float*)d_in[16];
  const float* bl_b  = (const float*)d_in[17];
  const float* W_ioc = (const float*)d_in[18];
  const float* U_ioc = (const float*)d_in[19];
  const float* b_ioc = (const float*)d_in[20];
  const float* Wf    = (const float*)d_in[21];
  const float* Uf    = (const float*)d_in[22];
  const float* bf    = (const float*)d_in[23];
  const float* W1    = (const float*)d_in[24];
  const float* b1    = (const float*)d_in[25];
  const float* W2    = (const float*)d_in[26];
  const float* b2    = (const float*)d_in[27];
  float* P_out = (float*)d_out;

  char* ws = (char*)d_ws;
  uint32_t* slotbase = (uint32_t*)(ws + 8192);           // 2048 u32 capacity
  float* fws = (float*)(ws + 65536);
  size_t off = 0;
  float* Xg    = fws + off; off += (size_t)16384 * 2048;
  float* blstm = fws + off; off += (size_t)SEQB * BATCH * HH2;
  float* attnv = fws + off; off += (size_t)SEQB * BATCH;
  float* Hent  = fws + off; off += (size_t)2048 * 512;
  float* Tall  = fws + off; off += (size_t)96 * BATCH * NROWS;
  unsigned long long* hxbuf = (unsigned long long*)(fws + off);
  off += (size_t)2 * 64 * 256 * 2;           // qwords = 2 floats each
  float* Ucat  = fws + off; off += (size_t)NROWS * 512;
  float* WE    = fws + off; off += (size_t)128 * 2048;   // [el][1536 ioc | 512 f]
  float* Mmat  = fws + off; off += 1024;
  float* mbv   = fws + off; off += 16;
  float* hbuf  = fws + off; off += (size_t)1024 * 512;
  const size_t needed = 65536 + off * sizeof(float);
  if (ws_size < needed) return;   // workspace too small: bail (visible failure)

  hipMemsetAsync(d_ws, 0, 65536, stream);    // slotbase=0 (poll sentinel)
  // hxbuf must start as tag=0/value=0 (valid "h=0 at step 0" records)
  hipMemsetAsync(hxbuf, 0, (size_t)2 * 64 * 256 * 8, stream);
  // Sentinel-fill the RELATION region of Tall (slots >= NEnt*BATCH*NROWS):
  // 0x7F bytes -> 0x7F7F7F7F = 3.39e38, unproducible by bounded helper sums.
  // Entity region (first 64*32 slices) is fully written by the big GEMM.
  hipMemsetAsync(Tall + (size_t)NEnt * BATCH * NROWS, 0x7F,
                 (size_t)32 * BATCH * NROWS * sizeof(float), stream);

  // 1) Xg = gather(word_emb, tokens) @ [Wih_f;Wih_b].T + [bl_f;bl_b]
  gemm_tn<1, 0><<<dim3(2048 / 128, 16384 / 128), 256, 0, stream>>>(
      nullptr, tokens, word_emb, Wih_f, Wih_b, 1024, bl_f, bl_b, 1024,
      Xg, 16384, 2048, 256);

  // 2) recurrent BiLSTM (quarter-split, tagged h exchange, resident weights)
  lstm_esplit<<<256, 256, 0, stream>>>(Xg, Whh_f, Whh_b, hxbuf, blstm);

  // 3) attention scores + entity H
  attn_k<<<4096, 256, 0, stream>>>(blstm, attn_w, attn_b, attnv);
  entity_prep<<<2048, 64, 0, stream>>>(spans, attnv, blstm, Hent, P_out);

  // 4) DAG-LSTM precompute
  pack_ucat<<<NROWS, 128, 0, stream>>>(U_ioc, Uf, Ucat);
  // WE[el] = [b_ioc + elem_emb[el] @ W_ioc.T | bf + elem_emb[el] @ Wf.T]
  gemm_tn<0, 1><<<dim3(2048 / 128, 1), 256, 0, stream>>>(
      elem_emb, nullptr, nullptr, W_ioc, Wf, 1536, b_ioc, bf, 1536,
      WE, 128, 2048, 128);
  mprep<<<1, 256, 0, stream>>>(W1, b1, W2, b2, Mmat, mbv);
  gemm_tn<0, 0><<<dim3(NROWS / 128, 2048 / 128), 256, 0, stream>>>(
      Hent, nullptr, nullptr, Ucat, nullptr, 0x40000000, nullptr, nullptr, 0,
      Tall, 2048, NROWS, 512);

  // 5) sequential DAG-LSTM with helper projection grid
  dag_seq<<<NHELP + 1, 512, 0, stream>>>(S, T, enames, entsz, WE, Mmat, mbv,
                                         Tall, hbuf, slotbase, Ucat, P_out);
}